// Round 8
// baseline (551.444 us; speedup 1.0000x reference)
//
#include <hip/hip_runtime.h>
#include <cstddef>

#define NN 262144
#define F_DIM 128
#define G_SEG 4096
#define H_DIM 512
#define SEG_SZ 64
#define KDIM 1024   // 2H
#define NDIM 2048   // 4H
#define KA 640      // reduced GEMM K: 512 (h) + 128 (fsum)

typedef unsigned short u16;
typedef __attribute__((ext_vector_type(8))) __bf16 bf16x8;
typedef __attribute__((ext_vector_type(4))) float f32x4;

__device__ __forceinline__ float hsig(float x) {
    return fminf(fmaxf(0.2f * x + 0.5f, 0.0f), 1.0f);
}

__device__ __forceinline__ u16 f2bf(float x) {
    union { float f; unsigned u; } v; v.f = x;
    unsigned r = (v.u + 0x7fffu + ((v.u >> 16) & 1u)) >> 16;
    return (u16)r;
}

// m_weight (F,H) -> mwT (H,F)
__global__ void k_transpose(const float* __restrict__ mw, float* __restrict__ mwT) {
    int id = blockIdx.x * blockDim.x + threadIdx.x;
    if (id < F_DIM * H_DIM) {
        int f = id / H_DIM, j = id % H_DIM;
        mwT[j * F_DIM + f] = mw[id];
    }
}

// Row permutation: original z-column n -> B-row rn so GEMM block bx owns all 4 gates
// of j-strip [bx*32, bx*32+32):  q=n>>9, jj=n&511, rn=(jj>>5)*128 + q*32 + (jj&31)
__device__ __forceinline__ int permrow(int n) {
    int q = n >> 9, jj = n & 511;
    return (jj >> 5) * 128 + q * 32 + (jj & 31);
}

// RK top 512 rows (h part) -> btg2 cols 0..511 (bf16, permuted rows, stride KA)
__global__ __launch_bounds__(256) void k_bt(const float* __restrict__ rk, u16* __restrict__ btg2) {
    __shared__ u16 t[64][65];
    int tid = threadIdx.x;
    int n0 = blockIdx.x * 64, k0 = blockIdx.y * 64;
    for (int i = tid; i < 64 * 64; i += 256) {
        int r = i >> 6, cc = i & 63;
        t[r][cc] = f2bf(rk[(size_t)(k0 + r) * NDIM + n0 + cc]);
    }
    __syncthreads();
    for (int i = tid; i < 64 * 64; i += 256) {
        int n = i >> 6, k = i & 63;
        btg2[(size_t)permrow(n0 + n) * KA + k0 + k] = t[k][n];
    }
}

// M2 = mw @ RK[512:1024,:]  (128 x 2048), written bf16 into btg2 cols 512..639
__global__ __launch_bounds__(256) void k_M2(const float* __restrict__ rk,
                                            const float* __restrict__ mwT,
                                            u16* __restrict__ btg2) {
    __shared__ float srk[64][64];    // [kk][nn] 16 KB
    __shared__ float smw[64][128];   // [kk][f]  32 KB
    int n0 = blockIdx.x * 64;
    int t = threadIdx.x;
    int f = t & 127, nh = t >> 7;    // nh in 0..1
    float acc[32] = {};
    for (int k0 = 0; k0 < H_DIM; k0 += 64) {
        for (int i = t; i < 64 * 64; i += 256) {
            int kk = i >> 6, nn = i & 63;
            srk[kk][nn] = rk[(size_t)(512 + k0 + kk) * NDIM + n0 + nn];
        }
        for (int i = t; i < 64 * 128; i += 256) {
            int ff = i & 127, kk = i >> 7;
            smw[kk][ff] = mwT[(size_t)(k0 + kk) * F_DIM + ff];
        }
        __syncthreads();
        for (int kk = 0; kk < 64; ++kk) {
            float w = smw[kk][f];
#pragma unroll
            for (int s = 0; s < 32; ++s)
                acc[s] = fmaf(w, srk[kk][nh * 32 + s], acc[s]);
        }
        __syncthreads();
    }
    for (int s = 0; s < 32; ++s) {
        int n = n0 + nh * 32 + s;
        btg2[(size_t)permrow(n) * KA + 512 + f] = f2bf(acc[s]);
    }
}

// rb2[n] = rb[n] + sum_j mb[j] * RK[512+j][n]   (bias absorbing mb @ RK_bot)
__global__ __launch_bounds__(256) void k_rb2(const float* __restrict__ rk,
                                             const float* __restrict__ rb,
                                             const float* __restrict__ mb,
                                             float* __restrict__ rb2) {
    int n = blockIdx.x * 256 + threadIdx.x;
    float acc = rb[n];
    for (int j = 0; j < H_DIM; ++j)
        acc = fmaf(mb[j], rk[(size_t)(512 + j) * NDIM + n], acc);
    rb2[n] = acc;
}

// Fused z-GEMM (K=640) + LSTM gates. A = qsa [4096][640] bf16 = [h | fsum],
// B = btg2 [2048][640] bf16 permuted. Wave owns 32 rows x 128 cols (all 4 gates).
#define GBM 128
#define GBK 32
__global__ __launch_bounds__(256) void k_gemm_gates(const u16* __restrict__ A,
                                                    const u16* __restrict__ BTG,
                                                    const float* __restrict__ rb2,
                                                    float* __restrict__ c,
                                                    float* __restrict__ out,
                                                    u16* __restrict__ qsa) {
    __shared__ u16 sA[GBM * GBK];
    __shared__ u16 sB[GBM * GBK];
    int tid = threadIdx.x;
    int lane = tid & 63, wv = tid >> 6;
    int wm = wv * 32;
    int bm = blockIdx.y * GBM;
    int j0 = blockIdx.x * 32;
    const u16* Ab = A + (size_t)bm * KA;
    const u16* Bb = BTG + (size_t)(blockIdx.x * 128) * KA;
    int r16 = lane & 15, kc = lane >> 4;
    f32x4 acc[2][8] = {};

    for (int k0 = 0; k0 < KA; k0 += GBK) {
#pragma unroll
        for (int i = 0; i < 2; ++i) {
            int ch = i * 256 + tid;            // 0..511
            int row = ch >> 2, cc = ch & 3;
            int ccs = cc ^ ((row >> 1) & 3);
            __builtin_amdgcn_global_load_lds(
                (const __attribute__((address_space(1))) void*)(Ab + (size_t)row * KA + k0 + ccs * 8),
                (__attribute__((address_space(3))) void*)(&sA[ch * 8]), 16, 0, 0);
            __builtin_amdgcn_global_load_lds(
                (const __attribute__((address_space(1))) void*)(Bb + (size_t)row * KA + k0 + ccs * 8),
                (__attribute__((address_space(3))) void*)(&sB[ch * 8]), 16, 0, 0);
        }
        __syncthreads();
        bf16x8 af[2], bfr[8];
#pragma unroll
        for (int mi = 0; mi < 2; ++mi) {
            int row = wm + mi * 16 + r16;
            int off = row * GBK + ((kc ^ ((row >> 1) & 3)) * 8);
            af[mi] = *reinterpret_cast<const bf16x8*>(&sA[off]);
        }
#pragma unroll
        for (int ni = 0; ni < 8; ++ni) {
            int row = ni * 16 + r16;
            int off = row * GBK + ((kc ^ ((row >> 1) & 3)) * 8);
            bfr[ni] = *reinterpret_cast<const bf16x8*>(&sB[off]);
        }
#pragma unroll
        for (int mi = 0; mi < 2; ++mi)
#pragma unroll
            for (int ni = 0; ni < 8; ++ni)
                acc[mi][ni] = __builtin_amdgcn_mfma_f32_16x16x32_bf16(af[mi], bfr[ni], acc[mi][ni], 0, 0, 0);
        __syncthreads();
    }

    float rbv[4][2];
#pragma unroll
    for (int q = 0; q < 4; ++q) {
        rbv[q][0] = rb2[q * H_DIM + j0 + r16];
        rbv[q][1] = rb2[q * H_DIM + j0 + 16 + r16];
    }
#pragma unroll
    for (int mi = 0; mi < 2; ++mi)
#pragma unroll
        for (int r = 0; r < 4; ++r) {
            int row = bm + wm + mi * 16 + kc * 4 + r;
#pragma unroll
            for (int jj = 0; jj < 2; ++jj) {
                int j = j0 + jj * 16 + r16;
                float zi = acc[mi][0 + jj][r] + rbv[0][jj];
                float zf = acc[mi][2 + jj][r] + rbv[1][jj];
                float zc = acc[mi][4 + jj][r] + rbv[2][jj];
                float zo = acc[mi][6 + jj][r] + rbv[3][jj];
                size_t ci = (size_t)row * H_DIM + j;
                float cn = hsig(zf) * c[ci] + hsig(zi) * tanhf(zc);
                c[ci] = cn;
                float h = hsig(zo) * tanhf(cn);
                out[(size_t)row * 1024 + j] = h;
                qsa[(size_t)row * KA + j] = f2bf(h);
            }
        }
}

// t=0: z == rb broadcast, c_prev == 0
__global__ void k_gates0(const float* __restrict__ rb,
                         float* __restrict__ c, float* __restrict__ out,
                         u16* __restrict__ qsa) {
    int id = blockIdx.x * blockDim.x + threadIdx.x;  // over G*H
    int g = id >> 9, j = id & 511;
    float zi = rb[j], zc = rb[2 * H_DIM + j], zo = rb[3 * H_DIM + j];
    float cn = hsig(zi) * tanhf(zc);
    c[id] = cn;
    float h = hsig(zo) * tanhf(cn);
    out[(size_t)g * 1024 + j] = h;
    qsa[(size_t)g * KA + j] = f2bf(h);
}

// Tiled W + folded bsum. 16 segments/block; mwT staged in LDS.
#define WSEG 16
__global__ __launch_bounds__(256) void k_W(const float* __restrict__ out,
                                           const float* __restrict__ mwT,
                                           const float* __restrict__ mb,
                                           float* __restrict__ W,
                                           float* __restrict__ bsum) {
    __shared__ float smw[128][F_DIM];   // 64 KB
    __shared__ float shl[WSEG][128];    // 8 KB
    __shared__ float smb[128];
    __shared__ float bacc[WSEG][16];
    int g0 = blockIdx.x * WSEG;
    int t = threadIdx.x;
    int f = t & 127, sh = t >> 7;
    bacc[t >> 4][t & 15] = 0.f;
    float acc[8] = {};
    for (int k0 = 0; k0 < H_DIM; k0 += 128) {
        for (int i = t; i < 128 * 32; i += 256) {
            int r = i >> 5, c4 = (i & 31) << 2;
            *reinterpret_cast<float4*>(&smw[r][c4]) =
                *reinterpret_cast<const float4*>(&mwT[(size_t)(k0 + r) * F_DIM + c4]);
        }
        for (int i = t; i < WSEG * 32; i += 256) {
            int s = i >> 5, c4 = (i & 31) << 2;
            *reinterpret_cast<float4*>(&shl[s][c4]) =
                *reinterpret_cast<const float4*>(&out[(size_t)(g0 + s) * 1024 + k0 + c4]);
        }
        if (t < 128) smb[t] = mb[k0 + t];
        __syncthreads();
        for (int kk = 0; kk < 128; ++kk) {
            float w = smw[kk][f];
#pragma unroll
            for (int s = 0; s < 8; ++s)
                acc[s] = fmaf(shl[sh + 2 * s][kk], w, acc[s]);
        }
        {   // bsum partials: thread (s, l16) owns 8 k-slots
            int s = t >> 4, l16 = t & 15;
            float pb = 0.f;
#pragma unroll
            for (int m = 0; m < 8; ++m)
                pb = fmaf(shl[s][l16 * 8 + m], smb[l16 * 8 + m], pb);
            bacc[s][l16] += pb;
        }
        __syncthreads();
    }
#pragma unroll
    for (int s = 0; s < 8; ++s)
        W[(size_t)(g0 + sh + 2 * s) * F_DIM + f] = acc[s];
    if (t < WSEG) {
        float b = 0.f;
#pragma unroll
        for (int i = 0; i < 16; ++i) b += bacc[t][i];
        bsum[g0 + t] = b;
    }
}

// per-segment attn; gmul=0 at t=0 (all W rows identical -> read row 0)
__global__ __launch_bounds__(128) void k_attn(const float* __restrict__ feats,
                                              const float* __restrict__ wts,
                                              const float* __restrict__ W,
                                              const float* __restrict__ bsum,
                                              float* __restrict__ fsum,
                                              u16* __restrict__ qsa,
                                              int gmul) {
    int g = blockIdx.x;
    int t = threadIdx.x;           // 0..127
    __shared__ float fl[SEG_SZ * 129];
    __shared__ float Wl[F_DIM];
    __shared__ float ep[2][SEG_SZ];
    __shared__ float al[SEG_SZ];
    const float4* f4 = reinterpret_cast<const float4*>(feats + (size_t)g * SEG_SZ * F_DIM);
    for (int i = t; i < SEG_SZ * F_DIM / 4; i += 128) {
        float4 v = f4[i];
        int n = i >> 5;
        int f = (i & 31) << 2;
        float* p = &fl[n * 129 + f];
        p[0] = v.x; p[1] = v.y; p[2] = v.z; p[3] = v.w;
    }
    Wl[t] = W[(size_t)(g * gmul) * F_DIM + t];
    __syncthreads();
    int row = t & 63, half = t >> 6;
    const float* fr = &fl[row * 129 + half * 64];
    const float* wr = &Wl[half * 64];
    float e = 0.f;
#pragma unroll
    for (int f = 0; f < 64; ++f) e = fmaf(fr[f], wr[f], e);
    ep[half][row] = e;
    __syncthreads();
    if (t < 64) {
        float ee = ep[0][t] + ep[1][t] + bsum[g * gmul];
        float mx = ee;
#pragma unroll
        for (int off = 32; off >= 1; off >>= 1) mx = fmaxf(mx, __shfl_xor(mx, off));
        float ex = expf(ee - mx) * wts[g * SEG_SZ + t];
        float s = ex;
#pragma unroll
        for (int off = 32; off >= 1; off >>= 1) s += __shfl_xor(s, off);
        al[t] = ex / s;
    }
    __syncthreads();
    float a0 = 0.f;
#pragma unroll
    for (int n = 0; n < SEG_SZ; ++n)
        a0 = fmaf(al[n], fl[n * 129 + t], a0);
    fsum[g * F_DIM + t] = a0;
    qsa[(size_t)g * KA + 512 + t] = f2bf(a0);   // fsum feeds next GEMM directly
}

// final r (t=2 only): r[g] = fsum[g] @ mw + mb -> out[:, H:2H]
#define RGB 8
__global__ __launch_bounds__(512) void k_r(const float* __restrict__ fsum,
                                           const float* __restrict__ mw,
                                           const float* __restrict__ mb,
                                           float* __restrict__ out) {
    int g0 = blockIdx.x * RGB;
    int tid = threadIdx.x;
    __shared__ float fs[RGB][F_DIM];
    for (int i = tid; i < RGB * F_DIM; i += 512)
        fs[i >> 7][i & 127] = fsum[g0 * F_DIM + i];
    __syncthreads();
    float acc[RGB] = {};
    for (int f = 0; f < F_DIM; ++f) {
        float w = mw[f * H_DIM + tid];
#pragma unroll
        for (int s = 0; s < RGB; ++s) acc[s] = fmaf(fs[s][f], w, acc[s]);
    }
    float bias = mb[tid];
#pragma unroll
    for (int s = 0; s < RGB; ++s)
        out[(size_t)(g0 + s) * 1024 + H_DIM + tid] = acc[s] + bias;
}

extern "C" void kernel_launch(void* const* d_in, const int* in_sizes, int n_in,
                              void* d_out, int out_size, void* d_ws, size_t ws_size,
                              hipStream_t stream) {
    const float* feats = (const float*)d_in[0];
    const float* wts   = (const float*)d_in[1];
    // d_in[2] = index: structurally n/64 — not needed
    const float* mw    = (const float*)d_in[3];
    const float* mb    = (const float*)d_in[4];
    const float* rk    = (const float*)d_in[5];
    const float* rb    = (const float*)d_in[6];
    float* out = (float*)d_out;

    float* c    = (float*)d_ws;                       // G*H
    float* W    = c + (size_t)G_SEG * H_DIM;          // G*F
    float* bs   = W + (size_t)G_SEG * F_DIM;          // G
    float* fsum = bs + G_SEG;                         // G*F
    float* mwT  = fsum + (size_t)G_SEG * F_DIM;       // H*F
    float* rb2  = mwT + (size_t)H_DIM * F_DIM;        // 4H
    u16*   qsa  = (u16*)(rb2 + NDIM);                 // G*KA bf16
    u16*   btg2 = qsa + (size_t)G_SEG * KA;           // NDIM*KA bf16

    k_transpose<<<(F_DIM * H_DIM + 255) / 256, 256, 0, stream>>>(mw, mwT);
    k_bt<<<dim3(NDIM / 64, 512 / 64), 256, 0, stream>>>(rk, btg2);
    k_M2<<<NDIM / 64, 256, 0, stream>>>(rk, mwT, btg2);
    k_rb2<<<NDIM / 256, 256, 0, stream>>>(rk, rb, mb, rb2);

    for (int t = 0; t < 3; ++t) {
        if (t > 0) {
            k_gemm_gates<<<dim3(H_DIM / 32, G_SEG / GBM), 256, 0, stream>>>(qsa, btg2, rb2, c, out, qsa);
        } else {
            k_gates0<<<(G_SEG * H_DIM) / 256, 256, 0, stream>>>(rb, c, out, qsa);
        }
        k_W<<<(t == 0) ? 1 : (G_SEG / WSEG), 256, 0, stream>>>(out, mwT, mb, W, bs);
        k_attn<<<G_SEG, 128, 0, stream>>>(feats, wts, W, bs, fsum, qsa, (t == 0) ? 0 : 1);
        if (t == 2)
            k_r<<<G_SEG / RGB, 512, 0, stream>>>(fsum, mw, mb, out);
    }
}

// Round 9
// 546.392 us; speedup vs baseline: 1.0092x; 1.0092x over previous
//
#include <hip/hip_runtime.h>
#include <cstddef>

#define NN 262144
#define F_DIM 128
#define G_SEG 4096
#define H_DIM 512
#define SEG_SZ 64
#define KDIM 1024   // 2H
#define NDIM 2048   // 4H
#define KA 640      // reduced GEMM K: 512 (h) + 128 (fsum)

typedef unsigned short u16;
typedef __attribute__((ext_vector_type(8))) __bf16 bf16x8;
typedef __attribute__((ext_vector_type(4))) float f32x4;

__device__ __forceinline__ float hsig(float x) {
    return fminf(fmaxf(0.2f * x + 0.5f, 0.0f), 1.0f);
}

__device__ __forceinline__ u16 f2bf(float x) {
    union { float f; unsigned u; } v; v.f = x;
    unsigned r = (v.u + 0x7fffu + ((v.u >> 16) & 1u)) >> 16;
    return (u16)r;
}

// m_weight (F,H) -> mwT (H,F)
__global__ void k_transpose(const float* __restrict__ mw, float* __restrict__ mwT) {
    int id = blockIdx.x * blockDim.x + threadIdx.x;
    if (id < F_DIM * H_DIM) {
        int f = id / H_DIM, j = id % H_DIM;
        mwT[j * F_DIM + f] = mw[id];
    }
}

// original z-column n -> B-row rn (block bx owns all 4 gates of its j-strip)
__device__ __forceinline__ int permrow(int n) {
    int q = n >> 9, jj = n & 511;
    return (jj >> 5) * 128 + q * 32 + (jj & 31);
}

// RK top 512 rows (h part) -> btg2 cols 0..511 (bf16, permuted rows, stride KA)
__global__ __launch_bounds__(256) void k_bt(const float* __restrict__ rk, u16* __restrict__ btg2) {
    __shared__ u16 t[64][65];
    int tid = threadIdx.x;
    int n0 = blockIdx.x * 64, k0 = blockIdx.y * 64;
    for (int i = tid; i < 64 * 64; i += 256) {
        int r = i >> 6, cc = i & 63;
        t[r][cc] = f2bf(rk[(size_t)(k0 + r) * NDIM + n0 + cc]);
    }
    __syncthreads();
    for (int i = tid; i < 64 * 64; i += 256) {
        int n = i >> 6, k = i & 63;
        btg2[(size_t)permrow(n0 + n) * KA + k0 + k] = t[k][n];
    }
}

// M2f += mw @ RK[512:1024,:] partials  (split-K atomic; grid (NDIM/32, 4))
__global__ __launch_bounds__(256) void k_M2(const float* __restrict__ rk,
                                            const float* __restrict__ mwT,
                                            float* __restrict__ M2f) {
    __shared__ float smw[128][F_DIM];   // [kk][f] 64 KB
    __shared__ float srk[128][32];      // [kk][nn] 16 KB
    int n0 = blockIdx.x * 32, k0 = blockIdx.y * 128;
    int t = threadIdx.x;
    for (int i = t; i < 128 * 32; i += 256) {
        int r = i >> 5, c4 = (i & 31) << 2;
        *reinterpret_cast<float4*>(&smw[r][c4]) =
            *reinterpret_cast<const float4*>(&mwT[(size_t)(k0 + r) * F_DIM + c4]);
    }
    for (int i = t; i < 128 * 32; i += 256) {
        int kk = i >> 5, nn = i & 31;
        srk[kk][nn] = rk[(size_t)(512 + k0 + kk) * NDIM + n0 + nn];
    }
    __syncthreads();
    int f = t & 127, h = t >> 7;
    float acc[16] = {};
    for (int kk = 0; kk < 128; ++kk) {
        float w = smw[kk][f];
#pragma unroll
        for (int s = 0; s < 16; ++s)
            acc[s] = fmaf(w, srk[kk][h * 16 + s], acc[s]);
    }
#pragma unroll
    for (int s = 0; s < 16; ++s)
        atomicAdd(&M2f[(size_t)f * NDIM + n0 + h * 16 + s], acc[s]);
}

// M2f (fp32, f-major) -> btg2 cols 512..639 bf16
__global__ __launch_bounds__(256) void k_M2cvt(const float* __restrict__ M2f,
                                               u16* __restrict__ btg2) {
    int id = blockIdx.x * 256 + threadIdx.x;     // over F*NDIM
    int f = id >> 11, n = id & 2047;
    btg2[(size_t)permrow(n) * KA + 512 + f] = f2bf(M2f[id]);
}

// rb2 += partials of rb + mb @ RK_bot  (split-K atomic; grid (NDIM/256, 4))
__global__ __launch_bounds__(256) void k_rb2(const float* __restrict__ rk,
                                             const float* __restrict__ rb,
                                             const float* __restrict__ mb,
                                             float* __restrict__ rb2) {
    int n = blockIdx.x * 256 + threadIdx.x;
    int j0 = blockIdx.y * 128;
    float acc = (blockIdx.y == 0) ? rb[n] : 0.f;
    for (int j = 0; j < 128; ++j)
        acc = fmaf(mb[j0 + j], rk[(size_t)(512 + j0 + j) * NDIM + n], acc);
    atomicAdd(&rb2[n], acc);
}

// Fused z-GEMM (K=640, 2-phase double-buffered) + LSTM gates.
// A = qin [4096][640] bf16 = [h | fsum] (prev iter), B = btg2 [2048][640] permuted.
// Writes h -> out[:, :H] and qout h-cols (race-free: qout != qin).
#define GBM 128
#define GBK 32
#define NKT (KA / GBK)   // 20
__global__ __launch_bounds__(256) void k_gemm_gates(const u16* __restrict__ A,
                                                    const u16* __restrict__ BTG,
                                                    const float* __restrict__ rb2,
                                                    float* __restrict__ c,
                                                    float* __restrict__ out,
                                                    u16* __restrict__ qout) {
    __shared__ u16 sA[2][GBM * GBK];
    __shared__ u16 sB[2][GBM * GBK];
    int tid = threadIdx.x;
    int lane = tid & 63, wv = tid >> 6;
    int wm = wv * 32;
    int bm = blockIdx.y * GBM;
    int j0 = blockIdx.x * 32;
    const u16* Ab = A + (size_t)bm * KA;
    const u16* Bb = BTG + (size_t)(blockIdx.x * 128) * KA;
    int r16 = lane & 15, kc = lane >> 4;
    f32x4 acc[2][8] = {};

    int srow = tid >> 2, scc = tid & 3;          // this thread's staging chunk geometry
    int sccs = scc ^ ((srow >> 1) & 3);          // source-side XOR swizzle
    int srow2 = (256 + tid) >> 2, scc2 = tid & 3;
    int sccs2 = scc2 ^ ((srow2 >> 1) & 3);

    // prologue: stage tile 0 into buf 0
    {
        __builtin_amdgcn_global_load_lds(
            (const __attribute__((address_space(1))) void*)(Ab + (size_t)srow * KA + sccs * 8),
            (__attribute__((address_space(3))) void*)(&sA[0][tid * 8]), 16, 0, 0);
        __builtin_amdgcn_global_load_lds(
            (const __attribute__((address_space(1))) void*)(Bb + (size_t)srow * KA + sccs * 8),
            (__attribute__((address_space(3))) void*)(&sB[0][tid * 8]), 16, 0, 0);
        __builtin_amdgcn_global_load_lds(
            (const __attribute__((address_space(1))) void*)(Ab + (size_t)srow2 * KA + sccs2 * 8),
            (__attribute__((address_space(3))) void*)(&sA[0][(256 + tid) * 8]), 16, 0, 0);
        __builtin_amdgcn_global_load_lds(
            (const __attribute__((address_space(1))) void*)(Bb + (size_t)srow2 * KA + sccs2 * 8),
            (__attribute__((address_space(3))) void*)(&sB[0][(256 + tid) * 8]), 16, 0, 0);
    }
    __syncthreads();

    for (int kt = 0; kt < NKT; ++kt) {
        int cur = kt & 1;
        if (kt < NKT - 1) {                       // issue next tile BEFORE compute
            int k0n = (kt + 1) * GBK;
            int nxt = cur ^ 1;
            __builtin_amdgcn_global_load_lds(
                (const __attribute__((address_space(1))) void*)(Ab + (size_t)srow * KA + k0n + sccs * 8),
                (__attribute__((address_space(3))) void*)(&sA[nxt][tid * 8]), 16, 0, 0);
            __builtin_amdgcn_global_load_lds(
                (const __attribute__((address_space(1))) void*)(Bb + (size_t)srow * KA + k0n + sccs * 8),
                (__attribute__((address_space(3))) void*)(&sB[nxt][tid * 8]), 16, 0, 0);
            __builtin_amdgcn_global_load_lds(
                (const __attribute__((address_space(1))) void*)(Ab + (size_t)srow2 * KA + k0n + sccs2 * 8),
                (__attribute__((address_space(3))) void*)(&sA[nxt][(256 + tid) * 8]), 16, 0, 0);
            __builtin_amdgcn_global_load_lds(
                (const __attribute__((address_space(1))) void*)(Bb + (size_t)srow2 * KA + k0n + sccs2 * 8),
                (__attribute__((address_space(3))) void*)(&sB[nxt][(256 + tid) * 8]), 16, 0, 0);
        }
        bf16x8 af[2], bfr[8];
#pragma unroll
        for (int mi = 0; mi < 2; ++mi) {
            int row = wm + mi * 16 + r16;
            int off = row * GBK + ((kc ^ ((row >> 1) & 3)) * 8);
            af[mi] = *reinterpret_cast<const bf16x8*>(&sA[cur][off]);
        }
#pragma unroll
        for (int ni = 0; ni < 8; ++ni) {
            int row = ni * 16 + r16;
            int off = row * GBK + ((kc ^ ((row >> 1) & 3)) * 8);
            bfr[ni] = *reinterpret_cast<const bf16x8*>(&sB[cur][off]);
        }
#pragma unroll
        for (int mi = 0; mi < 2; ++mi)
#pragma unroll
            for (int ni = 0; ni < 8; ++ni)
                acc[mi][ni] = __builtin_amdgcn_mfma_f32_16x16x32_bf16(af[mi], bfr[ni], acc[mi][ni], 0, 0, 0);
        __syncthreads();   // implicit vmcnt(0) drain: next tile ready, buffers safe to swap
    }

    float rbv[4][2];
#pragma unroll
    for (int q = 0; q < 4; ++q) {
        rbv[q][0] = rb2[q * H_DIM + j0 + r16];
        rbv[q][1] = rb2[q * H_DIM + j0 + 16 + r16];
    }
#pragma unroll
    for (int mi = 0; mi < 2; ++mi)
#pragma unroll
        for (int r = 0; r < 4; ++r) {
            int row = bm + wm + mi * 16 + kc * 4 + r;
#pragma unroll
            for (int jj = 0; jj < 2; ++jj) {
                int j = j0 + jj * 16 + r16;
                float zi = acc[mi][0 + jj][r] + rbv[0][jj];
                float zf = acc[mi][2 + jj][r] + rbv[1][jj];
                float zc = acc[mi][4 + jj][r] + rbv[2][jj];
                float zo = acc[mi][6 + jj][r] + rbv[3][jj];
                size_t ci = (size_t)row * H_DIM + j;
                float cn = hsig(zf) * c[ci] + hsig(zi) * tanhf(zc);
                c[ci] = cn;
                float h = hsig(zo) * tanhf(cn);
                out[(size_t)row * 1024 + j] = h;
                qout[(size_t)row * KA + j] = f2bf(h);
            }
        }
}

// t=0: z == rb broadcast, c_prev == 0
__global__ void k_gates0(const float* __restrict__ rb,
                         float* __restrict__ c, float* __restrict__ out,
                         u16* __restrict__ qout) {
    int id = blockIdx.x * blockDim.x + threadIdx.x;  // over G*H
    int g = id >> 9, j = id & 511;
    float zi = rb[j], zc = rb[2 * H_DIM + j], zo = rb[3 * H_DIM + j];
    float cn = hsig(zi) * tanhf(zc);
    c[id] = cn;
    float h = hsig(zo) * tanhf(cn);
    out[(size_t)g * 1024 + j] = h;
    qout[(size_t)g * KA + j] = f2bf(h);
}

// Tiled W + folded bsum. 16 segments/block; mwT staged in LDS.
#define WSEG 16
__global__ __launch_bounds__(256) void k_W(const float* __restrict__ out,
                                           const float* __restrict__ mwT,
                                           const float* __restrict__ mb,
                                           float* __restrict__ W,
                                           float* __restrict__ bsum) {
    __shared__ float smw[128][F_DIM];   // 64 KB
    __shared__ float shl[WSEG][128];    // 8 KB
    __shared__ float smb[128];
    __shared__ float bacc[WSEG][16];
    int g0 = blockIdx.x * WSEG;
    int t = threadIdx.x;
    int f = t & 127, sh = t >> 7;
    bacc[t >> 4][t & 15] = 0.f;
    float acc[8] = {};
    for (int k0 = 0; k0 < H_DIM; k0 += 128) {
        for (int i = t; i < 128 * 32; i += 256) {
            int r = i >> 5, c4 = (i & 31) << 2;
            *reinterpret_cast<float4*>(&smw[r][c4]) =
                *reinterpret_cast<const float4*>(&mwT[(size_t)(k0 + r) * F_DIM + c4]);
        }
        for (int i = t; i < WSEG * 32; i += 256) {
            int s = i >> 5, c4 = (i & 31) << 2;
            *reinterpret_cast<float4*>(&shl[s][c4]) =
                *reinterpret_cast<const float4*>(&out[(size_t)(g0 + s) * 1024 + k0 + c4]);
        }
        if (t < 128) smb[t] = mb[k0 + t];
        __syncthreads();
        for (int kk = 0; kk < 128; ++kk) {
            float w = smw[kk][f];
#pragma unroll
            for (int s = 0; s < 8; ++s)
                acc[s] = fmaf(shl[sh + 2 * s][kk], w, acc[s]);
        }
        {   // bsum partials: thread (s, l16) owns 8 k-slots
            int s = t >> 4, l16 = t & 15;
            float pb = 0.f;
#pragma unroll
            for (int m = 0; m < 8; ++m)
                pb = fmaf(shl[s][l16 * 8 + m], smb[l16 * 8 + m], pb);
            bacc[s][l16] += pb;
        }
        __syncthreads();
    }
#pragma unroll
    for (int s = 0; s < 8; ++s)
        W[(size_t)(g0 + sh + 2 * s) * F_DIM + f] = acc[s];
    if (t < WSEG) {
        float b = 0.f;
#pragma unroll
        for (int i = 0; i < 16; ++i) b += bacc[t][i];
        bsum[g0 + t] = b;
    }
}

// per-segment attn; gmul=0 at t=0 (all W rows identical -> read row 0)
__global__ __launch_bounds__(128) void k_attn(const float* __restrict__ feats,
                                              const float* __restrict__ wts,
                                              const float* __restrict__ W,
                                              const float* __restrict__ bsum,
                                              float* __restrict__ fsum,
                                              u16* __restrict__ qout,
                                              int gmul) {
    int g = blockIdx.x;
    int t = threadIdx.x;           // 0..127
    __shared__ float fl[SEG_SZ * 129];
    __shared__ float Wl[F_DIM];
    __shared__ float ep[2][SEG_SZ];
    __shared__ float al[SEG_SZ];
    const float4* f4 = reinterpret_cast<const float4*>(feats + (size_t)g * SEG_SZ * F_DIM);
    for (int i = t; i < SEG_SZ * F_DIM / 4; i += 128) {
        float4 v = f4[i];
        int n = i >> 5;
        int f = (i & 31) << 2;
        float* p = &fl[n * 129 + f];
        p[0] = v.x; p[1] = v.y; p[2] = v.z; p[3] = v.w;
    }
    Wl[t] = W[(size_t)(g * gmul) * F_DIM + t];
    __syncthreads();
    int row = t & 63, half = t >> 6;
    const float* fr = &fl[row * 129 + half * 64];
    const float* wr = &Wl[half * 64];
    float e = 0.f;
#pragma unroll
    for (int f = 0; f < 64; ++f) e = fmaf(fr[f], wr[f], e);
    ep[half][row] = e;
    __syncthreads();
    if (t < 64) {
        float ee = ep[0][t] + ep[1][t] + bsum[g * gmul];
        float mx = ee;
#pragma unroll
        for (int off = 32; off >= 1; off >>= 1) mx = fmaxf(mx, __shfl_xor(mx, off));
        float ex = expf(ee - mx) * wts[g * SEG_SZ + t];
        float s = ex;
#pragma unroll
        for (int off = 32; off >= 1; off >>= 1) s += __shfl_xor(s, off);
        al[t] = ex / s;
    }
    __syncthreads();
    float a0 = 0.f;
#pragma unroll
    for (int n = 0; n < SEG_SZ; ++n)
        a0 = fmaf(al[n], fl[n * 129 + t], a0);
    fsum[g * F_DIM + t] = a0;
    qout[(size_t)g * KA + 512 + t] = f2bf(a0);   // fsum feeds next GEMM
}

// final r (t=2 only): r[g] = fsum[g] @ mw + mb -> out[:, H:2H]
#define RGB 8
__global__ __launch_bounds__(512) void k_r(const float* __restrict__ fsum,
                                           const float* __restrict__ mw,
                                           const float* __restrict__ mb,
                                           float* __restrict__ out) {
    int g0 = blockIdx.x * RGB;
    int tid = threadIdx.x;
    __shared__ float fs[RGB][F_DIM];
    for (int i = tid; i < RGB * F_DIM; i += 512)
        fs[i >> 7][i & 127] = fsum[g0 * F_DIM + i];
    __syncthreads();
    float acc[RGB] = {};
    for (int f = 0; f < F_DIM; ++f) {
        float w = mw[f * H_DIM + tid];
#pragma unroll
        for (int s = 0; s < RGB; ++s) acc[s] = fmaf(fs[s][f], w, acc[s]);
    }
    float bias = mb[tid];
#pragma unroll
    for (int s = 0; s < RGB; ++s)
        out[(size_t)(g0 + s) * 1024 + H_DIM + tid] = acc[s] + bias;
}

extern "C" void kernel_launch(void* const* d_in, const int* in_sizes, int n_in,
                              void* d_out, int out_size, void* d_ws, size_t ws_size,
                              hipStream_t stream) {
    const float* feats = (const float*)d_in[0];
    const float* wts   = (const float*)d_in[1];
    // d_in[2] = index: structurally n/64 — not needed
    const float* mw    = (const float*)d_in[3];
    const float* mb    = (const float*)d_in[4];
    const float* rk    = (const float*)d_in[5];
    const float* rb    = (const float*)d_in[6];
    float* out = (float*)d_out;

    float* c    = (float*)d_ws;                       // G*H
    float* W    = c + (size_t)G_SEG * H_DIM;          // G*F
    float* bs   = W + (size_t)G_SEG * F_DIM;          // G
    float* fsum = bs + G_SEG;                         // G*F
    float* mwT  = fsum + (size_t)G_SEG * F_DIM;       // H*F
    float* rb2  = mwT + (size_t)H_DIM * F_DIM;        // 4H
    float* M2f  = rb2 + NDIM;                         // F*4H
    u16*   qsa0 = (u16*)(M2f + (size_t)F_DIM * NDIM); // G*KA bf16
    u16*   qsa1 = qsa0 + (size_t)G_SEG * KA;          // G*KA bf16
    u16*   btg2 = qsa1 + (size_t)G_SEG * KA;          // NDIM*KA bf16

    hipMemsetAsync(rb2, 0, NDIM * sizeof(float), stream);
    hipMemsetAsync(M2f, 0, (size_t)F_DIM * NDIM * sizeof(float), stream);
    k_transpose<<<(F_DIM * H_DIM + 255) / 256, 256, 0, stream>>>(mw, mwT);
    k_bt<<<dim3(NDIM / 64, 512 / 64), 256, 0, stream>>>(rk, btg2);
    k_M2<<<dim3(NDIM / 32, 4), 256, 0, stream>>>(rk, mwT, M2f);
    k_M2cvt<<<(F_DIM * NDIM) / 256, 256, 0, stream>>>(M2f, btg2);
    k_rb2<<<dim3(NDIM / 256, 4), 256, 0, stream>>>(rk, rb, mb, rb2);

    u16* qbuf[2] = {qsa0, qsa1};
    for (int t = 0; t < 3; ++t) {
        u16* qin  = qbuf[t & 1];        // t=1 reads qsa1? no: see mapping below
        u16* qout = qbuf[(t + 1) & 1];
        // mapping: t=0 writes qsa1(out slot for t=0), t=1 reads qsa1 writes qsa0, t=2 reads qsa0 writes qsa1
        if (t > 0) {
            k_gemm_gates<<<dim3(H_DIM / 32, G_SEG / GBM), 256, 0, stream>>>(qin, btg2, rb2, c, out, qout);
        } else {
            k_gates0<<<(G_SEG * H_DIM) / 256, 256, 0, stream>>>(rb, c, out, qout);
        }
        k_W<<<(t == 0) ? 1 : (G_SEG / WSEG), 256, 0, stream>>>(out, mwT, mb, W, bs);
        k_attn<<<G_SEG, 128, 0, stream>>>(feats, wts, W, bs, fsum, qout, (t == 0) ? 0 : 1);
        if (t == 2)
            k_r<<<G_SEG / RGB, 512, 0, stream>>>(fsum, mw, mb, out);
    }
}